// Round 20
// baseline (107.695 us; speedup 1.0000x reference)
//
#include <hip/hip_runtime.h>

// ---- problem constants ----
#define NIN 64
#define NOPS 1024
#define NB 2048
#define NNODES 1088            // NIN + NOPS
#define SLAB_SH 18             // node slot stride = 2048 rows * 128 B = 1<<18

// ---- workspace layout (bytes) ----
#define WS_SCHED 0u            // u64[1024] packed ops, sorted by (level, mat)
#define WS_LEV   8192u         // u32: [0]=nlev, [1]=slot of node 1087, [2]=err; +4096: u16 msta[2048]
#define WS_WT    16384u        // f16[8][64][128]  ([mat][n][k]), one-input mats zero-padded k>=64
#define WS_BIAS  147456u       // f32[512]
#define WS_NODES 163840u       // f16[cap][2048][64] slot slabs

// ---- k_main dynamic LDS layout (bytes) ----
#define LM_LINES 0u            // 2 x 64 lines x 512B = 65536
#define LM_SCHED 65536u        // u64[1024] = 8KB
#define LM_MSTA  73728u        // u16[2048] = 4KB (includes per-level full-barrier flags at 1600+L)
#define LM_TOTAL 77824u        // 76KB -> 2 blocks/CU

typedef unsigned int u32;
typedef unsigned short u16;
typedef unsigned long long u64;
typedef _Float16 f16;
typedef _Float16 f16x8 __attribute__((ext_vector_type(8)));
typedef _Float16 f16x4 __attribute__((ext_vector_type(4)));
typedef float f32x4 __attribute__((ext_vector_type(4)));

#define MFMA16(a, b, c) __builtin_amdgcn_mfma_f32_16x16x32_f16((a), (b), (c), 0, 0, 0)

// sched word bits (R8/R17 layout):
//  0-10 slot1 | 11-21 slot2 | 22-24 wx | 25-35 outslot
//  36-42 pos1, 43 fresh1 | 44-50 pos2, 51 fresh2 | 52-58 outpos, 59 ldsout | 60 globalout

// ------- merged: block 0 = ASAP scheduler; blocks 1..512 = weights+leaves prep -------
__global__ __launch_bounds__(1024) void k_sp(const int* __restrict__ ids,
                                             const float* __restrict__ emb,
                                             const float* __restrict__ oW,
                                             const float* __restrict__ ob,
                                             const float* __restrict__ tW,
                                             const float* __restrict__ tb,
                                             const int* __restrict__ wxv,
                                             const int* __restrict__ in1v,
                                             const int* __restrict__ in2v,
                                             char* __restrict__ ws, int cap) {
  const int tid = threadIdx.x;
  if (blockIdx.x != 0) {
    // ---------------- prep path (runs concurrently with scheduler) ----------------
    int bid = (int)blockIdx.x - 1;            // 0..511
    if (tid < 256) {                          // leaves: 512*256 = 131072 (i,b) pairs
      int p = bid * 256 + tid;
      int i = p >> 11, b = p & 2047;
      int id = ids[b * 64 + i];
      const f32x4* src = (const f32x4*)(emb + (u32)id * 64u);
      f16x8* dst = (f16x8*)(ws + WS_NODES + ((u32)i << SLAB_SH) + (u32)b * 128u);
      #pragma unroll
      for (int q = 0; q < 8; ++q) {
        f32x4 lo = src[2 * q], hi = src[2 * q + 1];
        f16x8 v = { (f16)lo.x, (f16)lo.y, (f16)lo.z, (f16)lo.w,
                    (f16)hi.x, (f16)hi.y, (f16)hi.z, (f16)hi.w };
        dst[q] = v;
      }
    } else if (tid < 512) {                   // weights: blocks 1..64
      if (bid < 64) {
        f16* wt = (f16*)(ws + WS_WT);
        int t = bid * 256 + (tid - 256);
        #pragma unroll
        for (int q = 0; q < 4; ++q) {
          int e = t * 4 + q;                  // e = mat*8192 + n*128 + k
          int mat = e >> 13, n = (e >> 7) & 63, k = e & 127;
          float v;
          if (mat < 4) v = (k < 64) ? oW[mat * 4096 + k * 64 + n] : 0.f;
          else         v = tW[(mat - 4) * 8192 + k * 64 + n];
          wt[e] = (f16)v;
        }
      }
    } else {                                  // bias: block 1
      if (bid == 0) {
        int q = tid - 512;                    // 0..511
        float* bs = (float*)(ws + WS_BIAS);
        bs[q] = (q < 256) ? ob[q] : tb[q - 256];
      }
    }
    return;
  }

  // ---------------- scheduler path (block 0, j = op id) ----------------
  __shared__ int s1[NOPS], s2[NOPS], sw[NOPS], slv[NOPS];
  __shared__ int lcnt[132];
  __shared__ int cnt2[1032];
  __shared__ u64 s_pack[NOPS];
  __shared__ int dl[NNODES], slot_of[NNODES];
  __shared__ int stk[2304];
  __shared__ int opPos[NOPS];
  __shared__ unsigned char needG[NOPS];
  __shared__ int s_flags[3];
  __shared__ int s_nlev, s_top, s_err;
  const int j = tid;
  s1[j] = in1v[j]; s2[j] = in2v[j]; sw[j] = wxv[j]; slv[j] = 1;
  needG[j] = 0;
  if (j < 132) lcnt[j] = 0;
  if (j < 1032) cnt2[j] = 0;
  if (j < 3) s_flags[j] = 0;
  if (j == 0) { s_nlev = 0; s_err = 0; }
  __syncthreads();
  // monotone relaxation, 1 barrier/iter via 3 rotating flags
  for (int it = 0; it < NOPS + 1; ++it) {
    int c = it % 3;
    int p1 = s1[j];
    int l1 = (p1 >= NIN) ? slv[p1 - NIN] : 0;
    int l2 = 0;
    if (sw[j] >= 4) { int p2 = s2[j]; l2 = (p2 >= NIN) ? slv[p2 - NIN] : 0; }
    int nl = 1 + (l1 > l2 ? l1 : l2);
    if (nl != slv[j]) { slv[j] = nl; s_flags[c] = 1; }
    if (j == 0) s_flags[(it + 1) % 3] = 0;
    __syncthreads();
    if (!s_flags[c]) break;         // uniform
  }
  atomicMax(&s_nlev, slv[j]);
  __syncthreads();
  u32* wl = (u32*)(ws + WS_LEV);
  const int nlev = s_nlev;
  if (nlev > 127) { if (j == 0) { wl[0] = 0; wl[1] = 0; wl[2] = 1; } return; }
  atomicAdd(&lcnt[slv[j]], 1);
  atomicAdd(&cnt2[slv[j] * 8 + sw[j]], 1);
  __syncthreads();
  if (j == 0) {
    int acc = 0;
    for (int L = 1; L <= nlev; ++L) { int c = lcnt[L]; lcnt[L] = acc; acc += c; }
  }
  __syncthreads();
  int base = -1;
  if (j >= 8 && j < (nlev + 1) * 8) {
    int L = j >> 3, mm = j & 7;
    int s = lcnt[L];
    for (int q = 0; q < mm; ++q) s += cnt2[L * 8 + q];
    base = s;
  }
  u16* msta = (u16*)(ws + WS_LEV + 4096);
  for (int t = j; t < 2048; t += 1024) msta[t] = (u16)NOPS;
  if (j < 128) msta[1600 + j] = 0;            // per-level full-barrier flags default 0
  __syncthreads();
  if (base >= 0) { cnt2[j] = base; msta[j] = (u16)base; }
  __syncthreads();
  { int slot = atomicAdd(&cnt2[slv[j] * 8 + sw[j]], 1);
    u64 p = (u64)(u32)s1[j] | ((u64)(u32)s2[j] << 11) | ((u64)(u32)sw[j] << 22) | ((u64)(u32)j << 25);
    s_pack[slot] = p;
    opPos[j] = slot - lcnt[slv[j]]; }
  __syncthreads();
  if (j == NOPS - 1) needG[j] = 1;
  { int L = slv[j];
    int i1n = s1[j];
    if (i1n >= NIN) { int p = i1n - NIN;
      if (!(slv[p] == L - 1 && opPos[p] < 64)) {
        needG[p] = 1;
        if (slv[p] == L - 1) msta[1600 + (L - 1)] = 1;   // gap-1 global edge: L-1's barrier must drain
      } }
    if (sw[j] >= 4) {
      int i2n = s2[j];
      if (i2n >= NIN) { int p = i2n - NIN;
        if (!(slv[p] == L - 1 && opPos[p] < 64)) {
          needG[p] = 1;
          if (slv[p] == L - 1) msta[1600 + (L - 1)] = 1;
        } }
    } }
  for (int t = j; t < NNODES; t += 1024) dl[t] = (t < NIN) ? 0 : slv[t - NIN];
  __syncthreads();
  atomicMax(&dl[s1[j]], slv[j]);
  if (sw[j] >= 4) atomicMax(&dl[s2[j]], slv[j]);
  __syncthreads();
  if (j == 0) dl[NNODES - 1] = nlev + 1;
  if (j < NIN) slot_of[j] = j;
  { int S = cap - 64; if (S > 1152) S = 1152;
    for (int t = j; t < S; t += 1024) stk[t] = 64 + t;
    if (j == 0) s_top = S; }
  __syncthreads();
  // coloring; slot reuse DELAYED one level (free at dl == L-2) so a load outstanding
  // across a light barrier can never race the reuse-store (>=1 full barrier between)
  for (int L = 1; L <= nlev; ++L) {
    for (int t = j; t < NNODES; t += 1024)
      if (dl[t] == L - 2) {
        int p = atomicAdd(&s_top, 1);
        if (p >= 0 && p < 2304) stk[p] = slot_of[t];
      }
    __syncthreads();
    if (slv[j] == L) {
      int p = atomicSub(&s_top, 1);
      int s;
      if (p >= 1) s = stk[p - 1]; else { s = 64; s_err = 1; }
      slot_of[NIN + j] = s;
    }
    __syncthreads();
  }
  {
    u64 m = s_pack[j];
    int i1n = (int)(m & 2047u), i2n = (int)((m >> 11) & 2047u);
    u32 wxn = (u32)((m >> 22) & 7u);
    int opn = (int)((m >> 25) & 2047u);
    int Lop = slv[opn];
    int two = (wxn >= 4);
    if (!two) i2n = i1n;
    u32 f1 = 0, p1 = 0, f2 = 0, p2 = 0;
    if (i1n >= NIN) { int p = i1n - NIN;
      if (slv[p] == Lop - 1 && opPos[p] < 64) { f1 = 1; p1 = (u32)opPos[p]; } }
    if (i2n >= NIN) { int p = i2n - NIN;
      if (slv[p] == Lop - 1 && opPos[p] < 64) { f2 = 1; p2 = (u32)opPos[p]; } }
    u32 op_pos = (u32)opPos[opn];
    u32 ldsout = (op_pos < 64) ? 1u : 0u;
    u32 gout   = needG[opn] ? 1u : 0u;
    u32 s1slot = (u32)slot_of[i1n];
    u32 s2slot = (u32)slot_of[i2n];
    u64 nm = (u64)s1slot | ((u64)s2slot << 11) | ((u64)wxn << 22)
           | ((u64)(u32)slot_of[NIN + opn] << 25)
           | ((u64)p1 << 36) | ((u64)f1 << 43)
           | ((u64)p2 << 44) | ((u64)f2 << 51)
           | ((u64)(op_pos & 63u) << 52) | ((u64)ldsout << 59)
           | ((u64)gout << 60);
    ((u64*)(ws + WS_SCHED))[j] = nm;
  }
  if (j == 0) {
    wl[0] = (u32)nlev;
    wl[1] = (u32)slot_of[NNODES - 1];
    wl[2] = s_err ? 1u : 0u;
  }
}

// ---------------- main: 4-op-packed MFMA + LDS fresh-cache + alternating light barriers ----------------
__global__ __launch_bounds__(512, 4) void k_main(char* __restrict__ ws,
                                                 const float* __restrict__ fw,
                                                 const float* __restrict__ fb,
                                                 float* __restrict__ out) {
  extern __shared__ char lds[];
  const int tid = threadIdx.x;
  const u32* wl = (const u32*)(ws + WS_LEV);
  if (wl[2]) return;               // uniform early-out before any barrier
  for (int t = tid; t < NOPS; t += 512)
    ((u64*)(lds + LM_SCHED))[t] = ((const u64*)(ws + WS_SCHED))[t];
  for (int t = tid; t < 1024; t += 512)
    ((u32*)(lds + LM_MSTA))[t] = ((const u32*)(ws + WS_LEV + 4096))[t];
  const int nlev = (int)wl[0];

  const int lane   = tid & 63;
  const int m      = tid >> 6;     // 8 waves, wave = its matrix (m<4 => one-input)
  const int lhi    = lane >> 4, llo = lane & 15;
  const int op_sub = llo >> 2;     // which of 4 packed ops this lane's column serves
  const int brow   = llo & 3;      // batch row within block
  const int r0     = blockIdx.x * 4;  // 512 blocks x 4 batch rows
  char* nodes = ws + WS_NODES;

  // W cache: FULL (64 cols x 128 k) slice of mat m; asm-pinned into VGPRs
  const f16* wp = (const f16*)(ws + WS_WT) + m * 8192 + llo * 128 + lhi * 8;
  f16x8 W00 = *(const f16x8*)(wp +        0), W01 = *(const f16x8*)(wp +       32),
        W10 = *(const f16x8*)(wp + 2048 + 0), W11 = *(const f16x8*)(wp + 2048 + 32),
        W20 = *(const f16x8*)(wp + 4096 + 0), W21 = *(const f16x8*)(wp + 4096 + 32),
        W30 = *(const f16x8*)(wp + 6144 + 0), W31 = *(const f16x8*)(wp + 6144 + 32);
  f16x8 W02 = {}, W03 = {}, W12 = {}, W13 = {}, W22 = {}, W23 = {}, W32 = {}, W33 = {};
  if (m >= 4) {
    W02 = *(const f16x8*)(wp +        64); W03 = *(const f16x8*)(wp +        96);
    W12 = *(const f16x8*)(wp + 2048 + 64); W13 = *(const f16x8*)(wp + 2048 + 96);
    W22 = *(const f16x8*)(wp + 4096 + 64); W23 = *(const f16x8*)(wp + 4096 + 96);
    W32 = *(const f16x8*)(wp + 6144 + 64); W33 = *(const f16x8*)(wp + 6144 + 96);
  }
  asm volatile("" : "+v"(W00), "+v"(W01), "+v"(W10), "+v"(W11),
                    "+v"(W20), "+v"(W21), "+v"(W30), "+v"(W31));
  asm volatile("" : "+v"(W02), "+v"(W03), "+v"(W12), "+v"(W13),
                    "+v"(W22), "+v"(W23), "+v"(W32), "+v"(W33));
  const float* bsp = (const float*)(ws + WS_BIAS) + m * 64 + lhi * 4;
  const f32x4 B0 = *(const f32x4*)(bsp),      B1 = *(const f32x4*)(bsp + 16),
              B2 = *(const f32x4*)(bsp + 32), B3 = *(const f32x4*)(bsp + 48);
  __syncthreads();

  const u64* s_sched = (const u64*)(lds + LM_SCHED);
  const u16* s_msta  = (const u16*)(lds + LM_MSTA);

  // per-lane global operand source: batch row brow, k chunk lhi
  const u32 a_off  = (u32)((r0 + brow) * 128 + lhi * 16);
  // per-lane global D: batch row brow; cols n = r*16 + lhi*4 + j
  const u32 st_off = (u32)((r0 + brow) * 128 + lhi * 8);
  // LDS line: 512B = 4 rows x 128B; byte(row,c) = row*128 + (c ^ (row<<4) ^ ((pos&3)<<5))
  const u32 key  = (u32)(brow << 4);
  const u32 bA   = (u32)(brow * 128);
  const u32 cA0  = (u32)((lhi * 16)      ^ key);
  const u32 cA1  = (u32)((lhi * 16 + 64) ^ key);
  const u32 cS0  = (u32)((      lhi * 8) ^ key);
  const u32 cS1  = (u32)(( 32 + lhi * 8) ^ key);
  const u32 cS2  = (u32)(( 64 + lhi * 8) ^ key);
  const u32 cS3  = (u32)(( 96 + lhi * 8) ^ key);

  for (int L = 1; L <= nlev; ++L) {
    const u32 rb = (u32)(((L - 1) & 1) << 15);   // read buffer (prev level)
    const u32 wb = (u32)((L & 1) << 15);         // write buffer (this level)
    int k0 = (int)s_msta[L * 8 + m];
    int k1 = (int)s_msta[L * 8 + m + 1];
    k0 = __builtin_amdgcn_readfirstlane(k0);
    k1 = __builtin_amdgcn_readfirstlane(k1);
    const int ke = k1 - 1;
    for (int g = k0; g < k1; g += 4) {         // 4 ops per iteration (packed in columns)
      int kop = g + op_sub; kop = kop > ke ? ke : kop;   // per-lane clamp (dup = benign)
      u64 md = s_sched[kop];
      f16x8 a0, a1;
      if ((md >> 43) & 1) {
        u32 pos = (u32)(md >> 36) & 63u;
        const char* l1 = lds + rb + (pos << 9);
        u32 px = (pos & 3u) << 5;
        a0 = *(const f16x8*)(l1 + bA + (cA0 ^ px));
        a1 = *(const f16x8*)(l1 + bA + (cA1 ^ px));
      } else {
        const char* b1 = nodes + ((u64)((u32)md & 2047u) << SLAB_SH) + a_off;
        a0 = *(const f16x8*)(b1);
        a1 = *(const f16x8*)(b1 + 64);
      }
      f16x8 a2 = {}, a3 = {};
      if (m >= 4) {
        if ((md >> 51) & 1) {
          u32 pos = (u32)(md >> 44) & 63u;
          const char* l2 = lds + rb + (pos << 9);
          u32 px = (pos & 3u) << 5;
          a2 = *(const f16x8*)(l2 + bA + (cA0 ^ px));
          a3 = *(const f16x8*)(l2 + bA + (cA1 ^ px));
        } else {
          const char* b2 = nodes + ((u64)(((u32)(md >> 11)) & 2047u) << SLAB_SH) + a_off;
          a2 = *(const f16x8*)(b2);
          a3 = *(const f16x8*)(b2 + 64);
        }
      }
      f32x4 c0 = B0, c1 = B1, c2 = B2, c3 = B3;
      __builtin_amdgcn_s_setprio(1);
      c0 = MFMA16(W00, a0, c0); c0 = MFMA16(W01, a1, c0);
      c1 = MFMA16(W10, a0, c1); c1 = MFMA16(W11, a1, c1);
      c2 = MFMA16(W20, a0, c2); c2 = MFMA16(W21, a1, c2);
      c3 = MFMA16(W30, a0, c3); c3 = MFMA16(W31, a1, c3);
      if (m >= 4) {
        c0 = MFMA16(W02, a2, c0); c0 = MFMA16(W03, a3, c0);
        c1 = MFMA16(W12, a2, c1); c1 = MFMA16(W13, a3, c1);
        c2 = MFMA16(W22, a2, c2); c2 = MFMA16(W23, a3, c2);
        c3 = MFMA16(W32, a2, c3); c3 = MFMA16(W33, a3, c3);
      }
      __builtin_amdgcn_s_setprio(0);
      f16x4 r0v = { (f16)(c0.x > 0.f ? c0.x : 0.f), (f16)(c0.y > 0.f ? c0.y : 0.f),
                    (f16)(c0.z > 0.f ? c0.z : 0.f), (f16)(c0.w > 0.f ? c0.w : 0.f) };
      f16x4 r1v = { (f16)(c1.x > 0.f ? c1.x : 0.f), (f16)(c1.y > 0.f ? c1.y : 0.f),
                    (f16)(c1.z > 0.f ? c1.z : 0.f), (f16)(c1.w > 0.f ? c1.w : 0.f) };
      f16x4 r2v = { (f16)(c2.x > 0.f ? c2.x : 0.f), (f16)(c2.y > 0.f ? c2.y : 0.f),
                    (f16)(c2.z > 0.f ? c2.z : 0.f), (f16)(c2.w > 0.f ? c2.w : 0.f) };
      f16x4 r3v = { (f16)(c3.x > 0.f ? c3.x : 0.f), (f16)(c3.y > 0.f ? c3.y : 0.f),
                    (f16)(c3.z > 0.f ? c3.z : 0.f), (f16)(c3.w > 0.f ? c3.w : 0.f) };
      if ((md >> 59) & 1) {                    // LDS line (fresh consumers next level)
        u32 opos = (u32)(md >> 52) & 63u;
        char* lp = lds + wb + (opos << 9);
        u32 px = (opos & 3u) << 5;
        *(f16x4*)(lp + bA + (cS0 ^ px)) = r0v;
        *(f16x4*)(lp + bA + (cS1 ^ px)) = r1v;
        *(f16x4*)(lp + bA + (cS2 ^ px)) = r2v;
        *(f16x4*)(lp + bA + (cS3 ^ px)) = r3v;
      }
      if ((md >> 60) & 1) {                    // global copy only when needed
        char* st = nodes + (((u64)((md >> 25) & 2047u)) << SLAB_SH) + st_off;
        *(f16x4*)(st)      = r0v;
        *(f16x4*)(st + 32) = r1v;
        *(f16x4*)(st + 64) = r2v;
        *(f16x4*)(st + 96) = r3v;
      }
    }
    // level boundary. Global edges have gap>=2 (or flagged), so odd levels may skip the
    // vmcnt(0) store-drain: stores stay in flight across the barrier (T4 pattern).
    {
      u32 lf = (u32)s_msta[1600 + L];
      lf = __builtin_amdgcn_readfirstlane(lf);
      const bool full = ((L & 1) == 0) || (lf != 0) || (L == nlev);
      __builtin_amdgcn_sched_barrier(0);
      if (full) { asm volatile("s_waitcnt vmcnt(0) lgkmcnt(0)" ::: "memory"); }
      else      { asm volatile("s_waitcnt lgkmcnt(0)" ::: "memory"); }
      __builtin_amdgcn_sched_barrier(0);
      __builtin_amdgcn_s_barrier();
      __builtin_amdgcn_sched_barrier(0);
    }
  }

  // fused final: out[r0+row] = dot(nodes[slot1087][r0+row], fw) + fb  (waves 0-3 -> rows 0-3)
  {
    u32 slot = wl[1];
    if (m < 4) {
      int row = m;
      const f16* src = (const f16*)(nodes + ((u64)slot << SLAB_SH) + (u32)(r0 + row) * 128u);
      float v = (float)src[lane] * fw[lane];
      v += __shfl_down(v, 32);
      v += __shfl_down(v, 16);
      v += __shfl_down(v, 8);
      v += __shfl_down(v, 4);
      v += __shfl_down(v, 2);
      v += __shfl_down(v, 1);
      if (lane == 0) out[r0 + row] = v + fb[0];
    }
  }
}

extern "C" void kernel_launch(void* const* d_in, const int* in_sizes, int n_in,
                              void* d_out, int out_size, void* d_ws, size_t ws_size,
                              hipStream_t stream) {
  const int*   ids = (const int*)d_in[0];
  const int*   wx  = (const int*)d_in[1];
  const int*   i1  = (const int*)d_in[2];
  const int*   i2  = (const int*)d_in[3];
  const float* emb = (const float*)d_in[4];
  const float* oW  = (const float*)d_in[5];
  const float* ob  = (const float*)d_in[6];
  const float* tW  = (const float*)d_in[7];
  const float* tb  = (const float*)d_in[8];
  const float* fw  = (const float*)d_in[9];
  const float* fb  = (const float*)d_in[10];
  char* ws = (char*)d_ws;
  float* out = (float*)d_out;

  int cap = (int)((ws_size > (size_t)WS_NODES) ? ((ws_size - WS_NODES) >> SLAB_SH) : 0);
  if (cap < 80) return;
  if (cap > 2047) cap = 2047;

  hipLaunchKernelGGL(k_sp,   dim3(513), dim3(1024), 0, stream,
                     ids, emb, oW, ob, tW, tb, wx, i1, i2, ws, cap);
  hipLaunchKernelGGL(k_main, dim3(512), dim3(512),  LM_TOTAL, stream, ws, fw, fb, out);
}

// Round 21
// 106.550 us; speedup vs baseline: 1.0107x; 1.0107x over previous
//
#include <hip/hip_runtime.h>

// ---- problem constants ----
#define NIN 64
#define NOPS 1024
#define NB 2048
#define NNODES 1088            // NIN + NOPS
#define SLAB_SH 18             // node slot stride = 2048 rows * 128 B = 1<<18

// ---- workspace layout (bytes) ----
#define WS_SCHED 0u            // u64[1024] packed ops, sorted by (level, mat)
#define WS_LEV   8192u         // u32: [0]=nlev, [1]=slot of node 1087, [2]=err; +4096: u16 msta[2048]
#define WS_WT    16384u        // f16[8][64][128]  ([mat][n][k]), one-input mats zero-padded k>=64
#define WS_BIAS  147456u       // f32[512]
#define WS_NODES 163840u       // f16[cap][2048][64] slot slabs

// ---- k_main dynamic LDS layout (bytes) ----
// 2 level-buffers x 64 lines x 512B (4 rows x 64 cols fp16, brow/pos-XOR swizzle) + tables
#define LM_LINES 0u            // 65536
#define LM_SCHED 65536u        // u64[1024] = 8KB
#define LM_MSTA  73728u        // u16[2048] = 4KB
#define LM_TOTAL 77824u        // 76KB -> 2 blocks/CU

typedef unsigned int u32;
typedef unsigned short u16;
typedef unsigned long long u64;
typedef _Float16 f16;
typedef _Float16 f16x8 __attribute__((ext_vector_type(8)));
typedef _Float16 f16x4 __attribute__((ext_vector_type(4)));
typedef float f32x4 __attribute__((ext_vector_type(4)));

#define MFMA16(a, b, c) __builtin_amdgcn_mfma_f32_16x16x32_f16((a), (b), (c), 0, 0, 0)

// sched word bits (R8/R17 layout):
//  0-10 slot1 | 11-21 slot2 | 22-24 wx | 25-35 outslot
//  36-42 pos1, 43 fresh1 | 44-50 pos2, 51 fresh2 | 52-58 outpos, 59 ldsout | 60 globalout

// ------- merged: block 0 = ASAP scheduler; blocks 1..512 = weights+leaves prep -------
__global__ __launch_bounds__(1024) void k_sp(const int* __restrict__ ids,
                                             const float* __restrict__ emb,
                                             const float* __restrict__ oW,
                                             const float* __restrict__ ob,
                                             const float* __restrict__ tW,
                                             const float* __restrict__ tb,
                                             const int* __restrict__ wxv,
                                             const int* __restrict__ in1v,
                                             const int* __restrict__ in2v,
                                             char* __restrict__ ws, int cap) {
  const int tid = threadIdx.x;
  if (blockIdx.x != 0) {
    // ---------------- prep path (runs concurrently with scheduler) ----------------
    int bid = (int)blockIdx.x - 1;            // 0..511
    if (tid < 256) {                          // leaves: 512*256 = 131072 (i,b) pairs
      int p = bid * 256 + tid;
      int i = p >> 11, b = p & 2047;
      int id = ids[b * 64 + i];
      const f32x4* src = (const f32x4*)(emb + (u32)id * 64u);
      f16x8* dst = (f16x8*)(ws + WS_NODES + ((u32)i << SLAB_SH) + (u32)b * 128u);
      #pragma unroll
      for (int q = 0; q < 8; ++q) {
        f32x4 lo = src[2 * q], hi = src[2 * q + 1];
        f16x8 v = { (f16)lo.x, (f16)lo.y, (f16)lo.z, (f16)lo.w,
                    (f16)hi.x, (f16)hi.y, (f16)hi.z, (f16)hi.w };
        dst[q] = v;
      }
    } else if (tid < 512) {                   // weights: blocks 1..64
      if (bid < 64) {
        f16* wt = (f16*)(ws + WS_WT);
        int t = bid * 256 + (tid - 256);
        #pragma unroll
        for (int q = 0; q < 4; ++q) {
          int e = t * 4 + q;                  // e = mat*8192 + n*128 + k
          int mat = e >> 13, n = (e >> 7) & 63, k = e & 127;
          float v;
          if (mat < 4) v = (k < 64) ? oW[mat * 4096 + k * 64 + n] : 0.f;
          else         v = tW[(mat - 4) * 8192 + k * 64 + n];
          wt[e] = (f16)v;
        }
      }
    } else {                                  // bias: block 1
      if (bid == 0) {
        int q = tid - 512;                    // 0..511
        float* bs = (float*)(ws + WS_BIAS);
        bs[q] = (q < 256) ? ob[q] : tb[q - 256];
      }
    }
    return;
  }

  // ---------------- scheduler path (block 0, j = op id) — R17 verbatim ----------------
  __shared__ int s1[NOPS], s2[NOPS], sw[NOPS], slv[NOPS];
  __shared__ int lcnt[132];
  __shared__ int cnt2[1032];
  __shared__ u64 s_pack[NOPS];
  __shared__ int dl[NNODES], slot_of[NNODES];
  __shared__ int stk[2304];
  __shared__ int opPos[NOPS];
  __shared__ unsigned char needG[NOPS];
  __shared__ int s_flags[3];
  __shared__ int s_nlev, s_top, s_err;
  const int j = tid;
  s1[j] = in1v[j]; s2[j] = in2v[j]; sw[j] = wxv[j]; slv[j] = 1;
  needG[j] = 0;
  if (j < 132) lcnt[j] = 0;
  if (j < 1032) cnt2[j] = 0;
  if (j < 3) s_flags[j] = 0;
  if (j == 0) { s_nlev = 0; s_err = 0; }
  __syncthreads();
  // monotone relaxation, 1 barrier/iter via 3 rotating flags
  for (int it = 0; it < NOPS + 1; ++it) {
    int c = it % 3;
    int p1 = s1[j];
    int l1 = (p1 >= NIN) ? slv[p1 - NIN] : 0;
    int l2 = 0;
    if (sw[j] >= 4) { int p2 = s2[j]; l2 = (p2 >= NIN) ? slv[p2 - NIN] : 0; }
    int nl = 1 + (l1 > l2 ? l1 : l2);
    if (nl != slv[j]) { slv[j] = nl; s_flags[c] = 1; }
    if (j == 0) s_flags[(it + 1) % 3] = 0;
    __syncthreads();
    if (!s_flags[c]) break;         // uniform
  }
  atomicMax(&s_nlev, slv[j]);
  __syncthreads();
  u32* wl = (u32*)(ws + WS_LEV);
  const int nlev = s_nlev;
  if (nlev > 127) { if (j == 0) { wl[0] = 0; wl[1] = 0; wl[2] = 1; } return; }
  atomicAdd(&lcnt[slv[j]], 1);
  atomicAdd(&cnt2[slv[j] * 8 + sw[j]], 1);
  __syncthreads();
  if (j == 0) {
    int acc = 0;
    for (int L = 1; L <= nlev; ++L) { int c = lcnt[L]; lcnt[L] = acc; acc += c; }
  }
  __syncthreads();
  int base = -1;
  if (j >= 8 && j < (nlev + 1) * 8) {
    int L = j >> 3, mm = j & 7;
    int s = lcnt[L];
    for (int q = 0; q < mm; ++q) s += cnt2[L * 8 + q];
    base = s;
  }
  u16* msta = (u16*)(ws + WS_LEV + 4096);
  for (int t = j; t < 2048; t += 1024) msta[t] = (u16)NOPS;
  __syncthreads();
  if (base >= 0) { cnt2[j] = base; msta[j] = (u16)base; }
  __syncthreads();
  { int slot = atomicAdd(&cnt2[slv[j] * 8 + sw[j]], 1);
    u64 p = (u64)(u32)s1[j] | ((u64)(u32)s2[j] << 11) | ((u64)(u32)sw[j] << 22) | ((u64)(u32)j << 25);
    s_pack[slot] = p;
    opPos[j] = slot - lcnt[slv[j]]; }
  __syncthreads();
  if (j == NOPS - 1) needG[j] = 1;
  { int L = slv[j];
    int i1n = s1[j];
    if (i1n >= NIN) { int p = i1n - NIN; if (!(slv[p] == L - 1 && opPos[p] < 64)) needG[p] = 1; }
    if (sw[j] >= 4) {
      int i2n = s2[j];
      if (i2n >= NIN) { int p = i2n - NIN; if (!(slv[p] == L - 1 && opPos[p] < 64)) needG[p] = 1; }
    } }
  for (int t = j; t < NNODES; t += 1024) dl[t] = (t < NIN) ? 0 : slv[t - NIN];
  __syncthreads();
  atomicMax(&dl[s1[j]], slv[j]);
  if (sw[j] >= 4) atomicMax(&dl[s2[j]], slv[j]);
  __syncthreads();
  if (j == 0) dl[NNODES - 1] = nlev + 1;
  if (j < NIN) slot_of[j] = j;
  { int S = cap - 64; if (S > 1152) S = 1152;
    for (int t = j; t < S; t += 1024) stk[t] = 64 + t;
    if (j == 0) s_top = S; }
  __syncthreads();
  for (int L = 1; L <= nlev; ++L) {
    for (int t = j; t < NNODES; t += 1024)
      if (dl[t] == L - 1) {
        int p = atomicAdd(&s_top, 1);
        if (p >= 0 && p < 2304) stk[p] = slot_of[t];
      }
    __syncthreads();
    if (slv[j] == L) {
      int p = atomicSub(&s_top, 1);
      int s;
      if (p >= 1) s = stk[p - 1]; else { s = 64; s_err = 1; }
      slot_of[NIN + j] = s;
    }
    __syncthreads();
  }
  {
    u64 m = s_pack[j];
    int i1n = (int)(m & 2047u), i2n = (int)((m >> 11) & 2047u);
    u32 wxn = (u32)((m >> 22) & 7u);
    int opn = (int)((m >> 25) & 2047u);
    int Lop = slv[opn];
    int two = (wxn >= 4);
    if (!two) i2n = i1n;
    u32 f1 = 0, p1 = 0, f2 = 0, p2 = 0;
    if (i1n >= NIN) { int p = i1n - NIN;
      if (slv[p] == Lop - 1 && opPos[p] < 64) { f1 = 1; p1 = (u32)opPos[p]; } }
    if (i2n >= NIN) { int p = i2n - NIN;
      if (slv[p] == Lop - 1 && opPos[p] < 64) { f2 = 1; p2 = (u32)opPos[p]; } }
    u32 op_pos = (u32)opPos[opn];
    u32 ldsout = (op_pos < 64) ? 1u : 0u;
    u32 gout   = needG[opn] ? 1u : 0u;
    u32 s1slot = (u32)slot_of[i1n];
    u32 s2slot = (u32)slot_of[i2n];
    u64 nm = (u64)s1slot | ((u64)s2slot << 11) | ((u64)wxn << 22)
           | ((u64)(u32)slot_of[NIN + opn] << 25)
           | ((u64)p1 << 36) | ((u64)f1 << 43)
           | ((u64)p2 << 44) | ((u64)f2 << 51)
           | ((u64)(op_pos & 63u) << 52) | ((u64)ldsout << 59)
           | ((u64)gout << 60);
    ((u64*)(ws + WS_SCHED))[j] = nm;
  }
  if (j == 0) {
    wl[0] = (u32)nlev;
    wl[1] = (u32)slot_of[NNODES - 1];
    wl[2] = s_err ? 1u : 0u;
  }
}

// ---------------- main: 4-op-packed MFMA + pinned W + LDS fresh-cache + fused final ----------------
__global__ __launch_bounds__(512, 4) void k_main(char* __restrict__ ws,
                                                 const float* __restrict__ fw,
                                                 const float* __restrict__ fb,
                                                 float* __restrict__ out) {
  extern __shared__ char lds[];
  const int tid = threadIdx.x;
  const u32* wl = (const u32*)(ws + WS_LEV);
  if (wl[2]) return;               // uniform early-out before any barrier
  for (int t = tid; t < NOPS; t += 512)
    ((u64*)(lds + LM_SCHED))[t] = ((const u64*)(ws + WS_SCHED))[t];
  for (int t = tid; t < 1024; t += 512)
    ((u32*)(lds + LM_MSTA))[t] = ((const u32*)(ws + WS_LEV + 4096))[t];
  const int nlev = (int)wl[0];

  const int lane   = tid & 63;
  const int m      = tid >> 6;     // 8 waves, wave = its matrix (m<4 => one-input)
  const int lhi    = lane >> 4, llo = lane & 15;
  const int op_sub = llo >> 2;     // which of 4 packed ops this lane's column serves
  const int brow   = llo & 3;      // batch row within block
  const int r0     = blockIdx.x * 4;  // 512 blocks x 4 batch rows
  char* nodes = ws + WS_NODES;

  // W cache: FULL (64 cols x 128 k) slice of mat m; asm-pinned into VGPRs
  const f16* wp = (const f16*)(ws + WS_WT) + m * 8192 + llo * 128 + lhi * 8;
  f16x8 W00 = *(const f16x8*)(wp +        0), W01 = *(const f16x8*)(wp +       32),
        W10 = *(const f16x8*)(wp + 2048 + 0), W11 = *(const f16x8*)(wp + 2048 + 32),
        W20 = *(const f16x8*)(wp + 4096 + 0), W21 = *(const f16x8*)(wp + 4096 + 32),
        W30 = *(const f16x8*)(wp + 6144 + 0), W31 = *(const f16x8*)(wp + 6144 + 32);
  f16x8 W02 = {}, W03 = {}, W12 = {}, W13 = {}, W22 = {}, W23 = {}, W32 = {}, W33 = {};
  if (m >= 4) {
    W02 = *(const f16x8*)(wp +        64); W03 = *(const f16x8*)(wp +        96);
    W12 = *(const f16x8*)(wp + 2048 + 64); W13 = *(const f16x8*)(wp + 2048 + 96);
    W22 = *(const f16x8*)(wp + 4096 + 64); W23 = *(const f16x8*)(wp + 4096 + 96);
    W32 = *(const f16x8*)(wp + 6144 + 64); W33 = *(const f16x8*)(wp + 6144 + 96);
  }
  asm volatile("" : "+v"(W00), "+v"(W01), "+v"(W10), "+v"(W11),
                    "+v"(W20), "+v"(W21), "+v"(W30), "+v"(W31));
  asm volatile("" : "+v"(W02), "+v"(W03), "+v"(W12), "+v"(W13),
                    "+v"(W22), "+v"(W23), "+v"(W32), "+v"(W33));
  const float* bsp = (const float*)(ws + WS_BIAS) + m * 64 + lhi * 4;
  const f32x4 B0 = *(const f32x4*)(bsp),      B1 = *(const f32x4*)(bsp + 16),
              B2 = *(const f32x4*)(bsp + 32), B3 = *(const f32x4*)(bsp + 48);
  __syncthreads();

  const u64* s_sched = (const u64*)(lds + LM_SCHED);
  const u16* s_msta  = (const u16*)(lds + LM_MSTA);

  // per-lane global operand source: batch row brow, k chunk lhi
  const u32 a_off  = (u32)((r0 + brow) * 128 + lhi * 16);
  // per-lane global D: batch row brow; cols n = r*16 + lhi*4 + j
  const u32 st_off = (u32)((r0 + brow) * 128 + lhi * 8);
  // LDS line: 512B = 4 rows x 128B; byte(row,c) = row*128 + (c ^ (row<<4) ^ ((pos&3)<<5))
  const u32 key  = (u32)(brow << 4);
  const u32 bA   = (u32)(brow * 128);
  const u32 cA0  = (u32)((lhi * 16)      ^ key);
  const u32 cA1  = (u32)((lhi * 16 + 64) ^ key);
  const u32 cS0  = (u32)((      lhi * 8) ^ key);
  const u32 cS1  = (u32)(( 32 + lhi * 8) ^ key);
  const u32 cS2  = (u32)(( 64 + lhi * 8) ^ key);
  const u32 cS3  = (u32)(( 96 + lhi * 8) ^ key);

  for (int L = 1; L <= nlev; ++L) {
    const u32 rb = (u32)(((L - 1) & 1) << 15);   // read buffer (prev level)
    const u32 wb = (u32)((L & 1) << 15);         // write buffer (this level)
    int k0 = (int)s_msta[L * 8 + m];
    int k1 = (int)s_msta[L * 8 + m + 1];
    k0 = __builtin_amdgcn_readfirstlane(k0);
    k1 = __builtin_amdgcn_readfirstlane(k1);
    const int ke = k1 - 1;
    for (int g = k0; g < k1; g += 4) {         // 4 ops per iteration (packed in columns)
      int kop = g + op_sub; kop = kop > ke ? ke : kop;   // per-lane clamp (dup = benign)
      u64 md = s_sched[kop];
      f16x8 a0, a1;
      if ((md >> 43) & 1) {
        u32 pos = (u32)(md >> 36) & 63u;
        const char* l1 = lds + rb + (pos << 9);
        u32 px = (pos & 3u) << 5;
        a0 = *(const f16x8*)(l1 + bA + (cA0 ^ px));
        a1 = *(const f16x8*)(l1 + bA + (cA1 ^ px));
      } else {
        const char* b1 = nodes + ((u64)((u32)md & 2047u) << SLAB_SH) + a_off;
        a0 = *(const f16x8*)(b1);
        a1 = *(const f16x8*)(b1 + 64);
      }
      f16x8 a2 = {}, a3 = {};
      if (m >= 4) {
        if ((md >> 51) & 1) {
          u32 pos = (u32)(md >> 44) & 63u;
          const char* l2 = lds + rb + (pos << 9);
          u32 px = (pos & 3u) << 5;
          a2 = *(const f16x8*)(l2 + bA + (cA0 ^ px));
          a3 = *(const f16x8*)(l2 + bA + (cA1 ^ px));
        } else {
          const char* b2 = nodes + ((u64)(((u32)(md >> 11)) & 2047u) << SLAB_SH) + a_off;
          a2 = *(const f16x8*)(b2);
          a3 = *(const f16x8*)(b2 + 64);
        }
      }
      f32x4 c0 = B0, c1 = B1, c2 = B2, c3 = B3;
      __builtin_amdgcn_s_setprio(1);
      c0 = MFMA16(W00, a0, c0); c0 = MFMA16(W01, a1, c0);
      c1 = MFMA16(W10, a0, c1); c1 = MFMA16(W11, a1, c1);
      c2 = MFMA16(W20, a0, c2); c2 = MFMA16(W21, a1, c2);
      c3 = MFMA16(W30, a0, c3); c3 = MFMA16(W31, a1, c3);
      if (m >= 4) {
        c0 = MFMA16(W02, a2, c0); c0 = MFMA16(W03, a3, c0);
        c1 = MFMA16(W12, a2, c1); c1 = MFMA16(W13, a3, c1);
        c2 = MFMA16(W22, a2, c2); c2 = MFMA16(W23, a3, c2);
        c3 = MFMA16(W32, a2, c3); c3 = MFMA16(W33, a3, c3);
      }
      __builtin_amdgcn_s_setprio(0);
      f16x4 r0v = { (f16)(c0.x > 0.f ? c0.x : 0.f), (f16)(c0.y > 0.f ? c0.y : 0.f),
                    (f16)(c0.z > 0.f ? c0.z : 0.f), (f16)(c0.w > 0.f ? c0.w : 0.f) };
      f16x4 r1v = { (f16)(c1.x > 0.f ? c1.x : 0.f), (f16)(c1.y > 0.f ? c1.y : 0.f),
                    (f16)(c1.z > 0.f ? c1.z : 0.f), (f16)(c1.w > 0.f ? c1.w : 0.f) };
      f16x4 r2v = { (f16)(c2.x > 0.f ? c2.x : 0.f), (f16)(c2.y > 0.f ? c2.y : 0.f),
                    (f16)(c2.z > 0.f ? c2.z : 0.f), (f16)(c2.w > 0.f ? c2.w : 0.f) };
      f16x4 r3v = { (f16)(c3.x > 0.f ? c3.x : 0.f), (f16)(c3.y > 0.f ? c3.y : 0.f),
                    (f16)(c3.z > 0.f ? c3.z : 0.f), (f16)(c3.w > 0.f ? c3.w : 0.f) };
      if ((md >> 59) & 1) {                    // LDS line (fresh consumers next level)
        u32 opos = (u32)(md >> 52) & 63u;
        char* lp = lds + wb + (opos << 9);
        u32 px = (opos & 3u) << 5;
        *(f16x4*)(lp + bA + (cS0 ^ px)) = r0v;
        *(f16x4*)(lp + bA + (cS1 ^ px)) = r1v;
        *(f16x4*)(lp + bA + (cS2 ^ px)) = r2v;
        *(f16x4*)(lp + bA + (cS3 ^ px)) = r3v;
      }
      if ((md >> 60) & 1) {                    // global copy only when needed
        char* st = nodes + (((u64)((md >> 25) & 2047u)) << SLAB_SH) + st_off;
        *(f16x4*)(st)      = r0v;
        *(f16x4*)(st + 32) = r1v;
        *(f16x4*)(st + 64) = r2v;
        *(f16x4*)(st + 96) = r3v;
      }
    }
    __syncthreads();   // level boundary: drains stores + LDS writes, orders RAW (8 waves)
  }

  // fused final: out[r0+row] = dot(nodes[slot1087][r0+row], fw) + fb  (waves 0-3 -> rows 0-3)
  {
    u32 slot = wl[1];
    if (m < 4) {
      int row = m;
      const f16* src = (const f16*)(nodes + ((u64)slot << SLAB_SH) + (u32)(r0 + row) * 128u);
      float v = (float)src[lane] * fw[lane];
      v += __shfl_down(v, 32);
      v += __shfl_down(v, 16);
      v += __shfl_down(v, 8);
      v += __shfl_down(v, 4);
      v += __shfl_down(v, 2);
      v += __shfl_down(v, 1);
      if (lane == 0) out[r0 + row] = v + fb[0];
    }
  }
}

extern "C" void kernel_launch(void* const* d_in, const int* in_sizes, int n_in,
                              void* d_out, int out_size, void* d_ws, size_t ws_size,
                              hipStream_t stream) {
  const int*   ids = (const int*)d_in[0];
  const int*   wx  = (const int*)d_in[1];
  const int*   i1  = (const int*)d_in[2];
  const int*   i2  = (const int*)d_in[3];
  const float* emb = (const float*)d_in[4];
  const float* oW  = (const float*)d_in[5];
  const float* ob  = (const float*)d_in[6];
  const float* tW  = (const float*)d_in[7];
  const float* tb  = (const float*)d_in[8];
  const float* fw  = (const float*)d_in[9];
  const float* fb  = (const float*)d_in[10];
  char* ws = (char*)d_ws;
  float* out = (float*)d_out;

  int cap = (int)((ws_size > (size_t)WS_NODES) ? ((ws_size - WS_NODES) >> SLAB_SH) : 0);
  if (cap < 80) return;
  if (cap > 2047) cap = 2047;

  hipLaunchKernelGGL(k_sp,   dim3(513), dim3(1024), 0, stream,
                     ids, emb, oW, ob, tW, tb, wx, i1, i2, ws, cap);
  hipLaunchKernelGGL(k_main, dim3(512), dim3(512),  LM_TOTAL, stream, ws, fw, fb, out);
}